// Round 10
// baseline (1992.044 us; speedup 1.0000x reference)
//
#include <hip/hip_runtime.h>

typedef __attribute__((ext_vector_type(4))) float f32x4;
typedef __attribute__((ext_vector_type(4))) unsigned int u32x4;
typedef __attribute__((ext_vector_type(4))) int i32x4;
typedef __attribute__((ext_vector_type(8))) int i32x8;
typedef unsigned char u8;
typedef unsigned short u16;
typedef unsigned int u32;

#define MBYTE (1024*1024)
#define TTOK 16384
#define HDIM 4096

// Interleaved operand layout (A and B both produced by our kernels):
// row-major 4096B rows of 32 K-tiles x 128B; within a tile, chunk c (16B)
// holds lane-fragment bytes; K-permutation identical for A and B, so any
// self-consistent HW K-mapping yields the same dot product (HW scales = 1.0).

__device__ __forceinline__ void gload_lds16(const void* g, void* l) {
  __builtin_amdgcn_global_load_lds((const __attribute__((address_space(1))) void*)g,
                                   (__attribute__((address_space(3))) void*)l, 16, 0, 0);
}

// ---- weight convert + transpose: W[k][n] f32 -> WT[n][k-interleaved] fp8 ----
__global__ __launch_bounds__(256) void k_wconv(const float* __restrict__ w0,
                                               const float* __restrict__ w1,
                                               const float* __restrict__ w2,
                                               u8* __restrict__ out) {
  __shared__ float tl[64][68];
  const int tid = threadIdx.x;
  const int bn = blockIdx.x, bk = blockIdx.y, z = blockIdx.z;
  const float* W = (z == 0) ? w0 : (z == 1 ? w1 : w2);
  u8* o = out + (size_t)z * 16 * MBYTE;
#pragma unroll
  for (int it = 0; it < 4; ++it) {
    int idx = it * 256 + tid;
    int r = idx >> 4, c4 = idx & 15;
    f32x4 v = *(const f32x4*)(W + (size_t)(bk * 64 + r) * HDIM + bn * 64 + c4 * 4);
    *(f32x4*)&tl[r][c4 * 4] = v;
  }
  __syncthreads();
  {
    int n = tid >> 2, q4 = tid & 3;
    u32 dw[4];
#pragma unroll
    for (int d = 0; d < 4; ++d) {
      int k0 = (d >> 1) * 32 + q4 * 8 + (d & 1) * 4;
      int w = __builtin_amdgcn_cvt_pk_fp8_f32(tl[k0 + 0][n], tl[k0 + 1][n], 0, false);
      w = __builtin_amdgcn_cvt_pk_fp8_f32(tl[k0 + 2][n], tl[k0 + 3][n], w, true);
      dw[d] = (u32)w;
    }
    u32x4 pack = {dw[0], dw[1], dw[2], dw[3]};
    *(u32x4*)(o + (size_t)(bn * 64 + n) * HDIM + (bk >> 1) * 128 + (bk & 1) * 64 + q4 * 16) = pack;
  }
}

// ---- fused elementwise: MODE 0: relu+rms+quant; 1: add+rms+quant; 2: add+rms->yout ----
// Group scale is rounded to bf16 FIRST, then used for quantization -> GEMM's
// bf16 dequant scale cancels exactly (no extra numeric error).
template <int MODE>
__global__ __launch_bounds__(256) void k_norm(const float* __restrict__ in,
                                              float* __restrict__ resid,
                                              const float* __restrict__ nw,
                                              u32* __restrict__ qout,
                                              u16* __restrict__ asct,
                                              float* __restrict__ yout) {
  const int row = blockIdx.x, t = threadIdx.x;
  const size_t base = (size_t)row * HDIM;
  const f32x4* inr = (const f32x4*)(in + base);
  f32x4* residr = (f32x4*)(resid + base);
  f32x4 v[4];
  float ss = 0.f;
#pragma unroll
  for (int j = 0; j < 4; ++j) {
    f32x4 a = inr[j * 256 + t];
    if (MODE == 0) {
      a.x = fmaxf(a.x, 0.f); a.y = fmaxf(a.y, 0.f);
      a.z = fmaxf(a.z, 0.f); a.w = fmaxf(a.w, 0.f);
    } else {
      f32x4 rz = residr[j * 256 + t];
      a.x += rz.x; a.y += rz.y; a.z += rz.z; a.w += rz.w;
    }
    if (MODE < 2) residr[j * 256 + t] = a;
    v[j] = a;
    ss += a.x * a.x + a.y * a.y + a.z * a.z + a.w * a.w;
  }
#pragma unroll
  for (int m = 1; m <= 32; m <<= 1) ss += __shfl_xor(ss, m, 64);
  __shared__ float sred[4];
  if ((t & 63) == 0) sred[t >> 6] = ss;
  __syncthreads();
  float tot = sred[0] + sred[1] + sred[2] + sred[3];
  float rinv = rsqrtf(tot * (1.f / (float)HDIM) + 1e-6f);
#pragma unroll
  for (int j = 0; j < 4; ++j) {
    f32x4 nv = ((const f32x4*)nw)[j * 256 + t];
    f32x4 y;
    y.x = v[j].x * rinv * nv.x; y.y = v[j].y * rinv * nv.y;
    y.z = v[j].z * rinv * nv.z; y.w = v[j].w * rinv * nv.w;
    if (MODE == 2) {
      ((f32x4*)yout)[(size_t)row * 1024 + j * 256 + t] = y;
    } else {
      float am = fmaxf(fmaxf(fabsf(y.x), fabsf(y.y)), fmaxf(fabsf(y.z), fabsf(y.w)));
#pragma unroll
      for (int m = 1; m <= 16; m <<= 1) am = fmaxf(am, __shfl_xor(am, m, 64));
      am = fmaxf(am, 1e-12f);
      float s = am * (1.f / 448.f);
      u32 x = __float_as_uint(s);
      u32 rb = (x + 0x7FFFu + ((x >> 16) & 1u)) >> 16;     // RNE to bf16
      float sbf = __uint_as_float(rb << 16);
      float inv = 1.0f / sbf;
      int d = __builtin_amdgcn_cvt_pk_fp8_f32(y.x * inv, y.y * inv, 0, false);
      d = __builtin_amdgcn_cvt_pk_fp8_f32(y.z * inv, y.w * inv, d, true);
      // interleaved layout: permute u32 index within each 32-u32 (128B) K-tile
      int k4 = j * 256 + t;
      int k4w = k4 & 31;
      int k4n = (k4 & ~31) | (((k4w >> 4) & 1) << 4) | (((k4w >> 1) & 3) << 2)
              | (((k4w >> 3) & 1) << 1) | (k4w & 1);
      qout[(size_t)row * 1024 + k4n] = (u32)d;
      if ((t & 31) == 0) asct[(size_t)(j * 8 + (t >> 5)) * TTOK + row] = (u16)rb;
    }
  }
}

// ---- fp8 block-scaled GEMM, 256x128 tile, 8 waves (64x64), BK=128, MX-rate MFMA.
// 3 LDS buffers, prefetch distance 2, stages issued INSIDE the body, ONE
// s_barrier per K-tile, counted vmcnt(6) (never drains in-flight prefetch).
__global__ __launch_bounds__(512, 1) void k_gemm(const u8* __restrict__ A,    // [T][4096] fp8 interleaved
                                                 const u8* __restrict__ B,    // [4096][4096] fp8 interleaved
                                                 const u16* __restrict__ aSb, // [32][T] bf16 scales
                                                 const float* __restrict__ bS, // [32][32]
                                                 float* __restrict__ C) {      // [T][4096]
  __shared__ u8 Al[3][256 * 128];   // 96KB
  __shared__ u8 Bl[3][128 * 128];   // 48KB
  __shared__ u8 AsB[32 * 256 * 2];  // 16KB bf16 act scales [kt][row]
  const int tid = threadIdx.x;
  const int lane = tid & 63, wave = tid >> 6;
  // XCD chunk (bijective, 2048 blocks) + 2bm x 4bn supertiles (~4MB L2 set)
  const int lin = blockIdx.x;
  const int xcd = lin & 7, tt = lin >> 3;
  const int sidx = tt >> 3, rr = tt & 7;
  const int sn = sidx & 7, sm = sidx >> 3;
  const int bm = xcd * 8 + sm * 2 + (rr >> 2);
  const int bn = sn * 4 + (rr & 3);
  const int brow = bm * 256, bcol = bn * 128;
  const int wrb = (wave >> 1) * 64, wcb = (wave & 1) * 64;   // 64x64 wave tile
  const int r16 = lane & 15, q4 = lane >> 4;
  const int swz3 = r16 & 7;
  const int c0 = (q4 ^ swz3) << 4;
  const int c1 = ((4 + q4) ^ swz3) << 4;

  // staging: A rows i*64 + (tid>>3) (i=0..3), B rows i*64 + (tid>>3) (i=0..1),
  // chunk (tid&7), inverse-swizzled source; LDS dest linear (uniform + tid*16)
  const int r0 = tid >> 3;
  const int sc = ((tid & 7) ^ (r0 & 7)) << 4;
  const u8* aP = A + (size_t)(brow + r0) * HDIM + sc;
  const u8* bP = B + (size_t)(bcol + r0) * HDIM + sc;
  const int ldst = tid * 16;

  // STAGE = 6 vmem instructions per thread (4 A + 2 B), 48KB/tile
#define STAGE(bi, kt) do {                                                      \
    _Pragma("unroll")                                                           \
    for (int i = 0; i < 4; ++i)                                                 \
      gload_lds16(aP + (size_t)(kt) * 128 + (size_t)i * 64 * HDIM,              \
                  &Al[bi][i * 8192 + ldst]);                                    \
    _Pragma("unroll")                                                           \
    for (int i = 0; i < 2; ++i)                                                 \
      gload_lds16(bP + (size_t)(kt) * 128 + (size_t)i * 64 * HDIM,              \
                  &Bl[bi][i * 8192 + ldst]);                                    \
  } while (0)

  // prologue: As fill (2 gloads) + tiles 0,1 (12 gloads); all guarded by the
  // kt=0 vmcnt(6)+barrier (As + tile0 retired, tile1 stays in flight).
  {
    const u8* asb = (const u8*)aSb;
#pragma unroll
    for (int j = 0; j < 2; ++j)
      gload_lds16(asb + (size_t)(j * 16 + (tid >> 5)) * (TTOK * 2) + brow * 2 + (tid & 31) * 16,
                  &AsB[j * 8192 + ldst]);
  }
  STAGE(0, 0);
  STAGE(1, 1);

  f32x4 accm[4][4] = {};
  const f32x4 z4 = {0.f, 0.f, 0.f, 0.f};
  int cur = 0;

#pragma unroll 1
  for (int kt = 0; kt < 32; ++kt) {
    if (kt < 31) asm volatile("s_waitcnt vmcnt(6)" ::: "memory");
    else         asm volatile("s_waitcnt vmcnt(0)" ::: "memory");
    __builtin_amdgcn_s_barrier();        // all waves' tile-kt stages landed
    __builtin_amdgcn_sched_barrier(0);   // nothing hoists above the barrier

    const float wsb = bS[kt * 32 + bn];  // wave-uniform -> SMEM
    const u8* AlC = &Al[cur][0];
    const u8* BlC = &Bl[cur][0];

    i32x8 bfr[4];
#pragma unroll
    for (int n = 0; n < 4; ++n) {
      const u8* rp = BlC + (wcb + n * 16 + r16) * 128;
      i32x4 lo = *(const i32x4*)(rp + c0);
      i32x4 hi = *(const i32x4*)(rp + c1);
      bfr[n] = __builtin_shufflevector(lo, hi, 0, 1, 2, 3, 4, 5, 6, 7);
    }

    // stage tile kt+2 into buf (cur+2)%3: safe (nobody reads it this kt or next)
    int s2 = cur + 2; if (s2 >= 3) s2 -= 3;
    if (kt < 30) STAGE(s2, kt + 2);

#pragma unroll
    for (int m = 0; m < 4; ++m) {
      const u8* rp = AlC + (wrb + m * 16 + r16) * 128;
      i32x4 lo = *(const i32x4*)(rp + c0);
      i32x4 hi = *(const i32x4*)(rp + c1);
      i32x8 afr = __builtin_shufflevector(lo, hi, 0, 1, 2, 3, 4, 5, 6, 7);
      const u32* spp = (const u32*)&AsB[kt * 512 + (wrb + m * 16 + q4 * 4) * 2];
      u32 sp0 = spp[0], sp1 = spp[1];
      f32x4 sa;
      sa.x = __uint_as_float(sp0 << 16);
      sa.y = __uint_as_float(sp0 & 0xFFFF0000u);
      sa.z = __uint_as_float(sp1 << 16);
      sa.w = __uint_as_float(sp1 & 0xFFFF0000u);
      const f32x4 s = sa * wsb;
      f32x4 acc[4];
      __builtin_amdgcn_s_setprio(1);
#pragma unroll
      for (int n = 0; n < 4; ++n)
        acc[n] = __builtin_amdgcn_mfma_scale_f32_16x16x128_f8f6f4(
            afr, bfr[n], z4, 0, 0, 0, 0x7F7F7F7F, 0, 0x7F7F7F7F);
      __builtin_amdgcn_s_setprio(0);
#pragma unroll
      for (int n = 0; n < 4; ++n)
        accm[m][n] += acc[n] * s;
    }
    cur = (cur == 2) ? 0 : cur + 1;
  }
#undef STAGE

#pragma unroll
  for (int m = 0; m < 4; ++m) {
#pragma unroll
    for (int r = 0; r < 4; ++r) {
      float* Cp = C + (size_t)(brow + wrb + m * 16 + q4 * 4 + r) * HDIM + bcol + wcb + r16;
#pragma unroll
      for (int n = 0; n < 4; ++n) Cp[n * 16] = accm[m][n][r];
    }
  }
}

extern "C" void kernel_launch(void* const* d_in, const int* in_sizes, int n_in,
                              void* d_out, int out_size, void* d_ws, size_t ws_size,
                              hipStream_t stream) {
  const float* x  = (const float*)d_in[0];
  const float* nw = (const float*)d_in[1];
  const float* w0 = (const float*)d_in[2];
  const float* w1 = (const float*)d_in[3];
  const float* w2 = (const float*)d_in[4];
  const float* s0 = (const float*)d_in[5];
  const float* s1 = (const float*)d_in[6];
  const float* s2 = (const float*)d_in[7];
  float* out = (float*)d_out;
  char* ws = (char*)d_ws;

  u8*  wqt   = (u8*)ws;                               // 3 x 16MB
  u32* q     = (u32*)(ws + (size_t)48 * MBYTE);       // 64MB fp8 activations
  u16* asc   = (u16*)(ws + (size_t)112 * MBYTE);      // 1MB  [32][T] bf16
  float* rsd = (float*)(ws + (size_t)114 * MBYTE);    // 256MB residual

  k_wconv<<<dim3(64, 64, 3), 256, 0, stream>>>(w0, w1, w2, wqt);

  k_norm<0><<<TTOK, 256, 0, stream>>>(x, rsd, nw, q, asc, nullptr);
  k_gemm<<<2048, 512, 0, stream>>>((const u8*)q, wqt, asc, s0, out);

  k_norm<1><<<TTOK, 256, 0, stream>>>(out, rsd, nw + HDIM, q, asc, nullptr);
  k_gemm<<<2048, 512, 0, stream>>>((const u8*)q, wqt + (size_t)16 * MBYTE, asc, s1, out);

  k_norm<1><<<TTOK, 256, 0, stream>>>(out, rsd, nw + 2 * HDIM, q, asc, nullptr);
  k_gemm<<<2048, 512, 0, stream>>>((const u8*)q, wqt + (size_t)32 * MBYTE, asc, s2, out);

  k_norm<2><<<TTOK, 256, 0, stream>>>(out, rsd, nw + 3 * HDIM, nullptr, nullptr, out);
}